// Round 9
// baseline (789.734 us; speedup 1.0000x reference)
//
#include <hip/hip_runtime.h>

#define D 128
#define NT 256
#define NBLK 1536                 // 6 blocks/CU; launch_bounds(256,8) caps VGPR -> all co-resident
#define HW_PER_BLK (NT / 32)      // 8 half-waves per block
#define NHW (NBLK * HW_PER_BLK)   // 12288 half-waves
#define ROWS 4                    // rows per half-wave per iteration

// k0: zero wsum + barrier counters (stream order makes this visible to k1)
__global__ __launch_bounds__(256) void zero_kernel(
    float* __restrict__ wsum, int n, int* __restrict__ bar)
{
    const int i = blockIdx.x * blockDim.x + threadIdx.x;
    if (i < n) wsum[i] = 0.f;
    if (blockIdx.x == 0 && threadIdx.x < 4) bar[threadIdx.x] = 0;
}

__device__ __forceinline__ void grid_barrier(int* bar, int target)
{
    __syncthreads();                       // drain this block's stores to L2
    if (threadIdx.x == 0) {
        __threadfence();                   // L2 writeback -> coherent point
        __hip_atomic_fetch_add(bar, 1, __ATOMIC_RELEASE, __HIP_MEMORY_SCOPE_AGENT);
        while (__hip_atomic_load(bar, __ATOMIC_ACQUIRE, __HIP_MEMORY_SCOPE_AGENT) < target)
            __builtin_amdgcn_s_sleep(1);
    }
    __syncthreads();
}

// One persistent kernel: P1 wsum scatter | P2 btw partials | P3 btw reduce |
// P4 snode scan | P5 out gather.  Barriers: bar[0..3].
__global__ __launch_bounds__(NT, 8) void fused_kernel(
    const float* __restrict__ embed,
    const float* __restrict__ weight,
    const int*   __restrict__ eidx,
    float* __restrict__ out,
    float* __restrict__ wsum,       // [nNodes] pre-zeroed
    float* __restrict__ btw,        // [D]
    float* __restrict__ partialT,   // [D][NBLK]
    float* __restrict__ snode,      // [nNodes]
    int*   __restrict__ bar,        // [4] pre-zeroed
    int nNodes, int nEdges)
{
    __shared__ float sbtw[D];
    __shared__ float red[NT];

    const int tid = threadIdx.x;
    const int t   = blockIdx.x * NT + tid;
    const int j   = tid & 31;                 // lane -> dims 4j..4j+3
    const int hw  = blockIdx.x * HW_PER_BLK + (tid >> 5);
    const int npair = nEdges >> 1;

    // ---- P1: wsum[dst] += w (2 edges/thread, one shot: npair < NBLK*NT) ----
    if (t < npair) {
        const int4   p = reinterpret_cast<const int4*>(eidx)[t];
        const float2 w = reinterpret_cast<const float2*>(weight)[t];
        unsafeAtomicAdd(&wsum[p.y], w.x);
        unsafeAtomicAdd(&wsum[p.w], w.y);
    }
    if ((nEdges & 1) && t == npair)
        unsafeAtomicAdd(&wsum[eidx[2 * npair + 1]], weight[npair]);

    for (int i = tid; i < D; i += NT) sbtw[i] = 0.f;   // init before barrier

    grid_barrier(&bar[0], NBLK);

    // ---- P2: per-block partial column sums (4 rows in flight per half-wave) ----
    {
        float4 acc = {0.f, 0.f, 0.f, 0.f};
        for (int base = 0; base < nNodes; base += NHW * ROWS) {
            const int n0 = base + hw * ROWS;
            if (n0 + ROWS <= nNodes) {
                float4 v[ROWS]; float w[ROWS];
                #pragma unroll
                for (int r = 0; r < ROWS; ++r)
                    v[r] = reinterpret_cast<const float4*>(embed + (size_t)(n0 + r) * D)[j];
                #pragma unroll
                for (int r = 0; r < ROWS; ++r) w[r] = wsum[n0 + r];
                #pragma unroll
                for (int r = 0; r < ROWS; ++r) {
                    acc.x += w[r] * v[r].x; acc.y += w[r] * v[r].y;
                    acc.z += w[r] * v[r].z; acc.w += w[r] * v[r].w;
                }
            } else {
                for (int r = 0; r < ROWS && n0 + r < nNodes; ++r) {
                    const float  w = wsum[n0 + r];
                    const float4 v = reinterpret_cast<const float4*>(embed + (size_t)(n0 + r) * D)[j];
                    acc.x += w * v.x; acc.y += w * v.y; acc.z += w * v.z; acc.w += w * v.w;
                }
            }
        }
        atomicAdd(&sbtw[4*j+0], acc.x);
        atomicAdd(&sbtw[4*j+1], acc.y);
        atomicAdd(&sbtw[4*j+2], acc.z);
        atomicAdd(&sbtw[4*j+3], acc.w);
        __syncthreads();
        if (tid < D) partialT[(size_t)tid * NBLK + blockIdx.x] = sbtw[tid];
    }

    grid_barrier(&bar[1], NBLK);

    // ---- P3: btw[d] = sum_b partialT[d][b]  (blocks 0..127) ----
    if (blockIdx.x < D) {
        const float* row = partialT + (size_t)blockIdx.x * NBLK;
        float s = 0.f;
        for (int k = tid; k < NBLK; k += NT) s += row[k];
        red[tid] = s;
        __syncthreads();
        for (int off = NT / 2; off > 0; off >>= 1) {
            if (tid < off) red[tid] += red[tid + off];
            __syncthreads();
        }
        if (tid == 0) btw[blockIdx.x] = red[0];
    }

    grid_barrier(&bar[2], NBLK);

    // ---- P4: snode[n] = dot(embed[n,:], btw) ----
    {
        const float4 bt = reinterpret_cast<const float4*>(btw)[j];
        for (int base = 0; base < nNodes; base += NHW * ROWS) {
            const int n0 = base + hw * ROWS;
            if (n0 + ROWS <= nNodes) {
                float4 v[ROWS];
                #pragma unroll
                for (int r = 0; r < ROWS; ++r)
                    v[r] = reinterpret_cast<const float4*>(embed + (size_t)(n0 + r) * D)[j];
                float s[ROWS];
                #pragma unroll
                for (int r = 0; r < ROWS; ++r)
                    s[r] = v[r].x*bt.x + v[r].y*bt.y + v[r].z*bt.z + v[r].w*bt.w;
                #pragma unroll
                for (int m = 1; m < 32; m <<= 1) {
                    #pragma unroll
                    for (int r = 0; r < ROWS; ++r) s[r] += __shfl_xor(s[r], m, 64);
                }
                if (j == 0) {
                    float4 o = {s[0], s[1], s[2], s[3]};
                    *reinterpret_cast<float4*>(snode + n0) = o;
                }
            } else {
                for (int r = 0; r < ROWS && n0 + r < nNodes; ++r) {
                    const float4 v = reinterpret_cast<const float4*>(embed + (size_t)(n0 + r) * D)[j];
                    float s = v.x*bt.x + v.y*bt.y + v.z*bt.z + v.w*bt.w;
                    #pragma unroll
                    for (int m = 1; m < 32; m <<= 1) s += __shfl_xor(s, m, 64);
                    if (j == 0) snode[n0 + r] = s;
                }
            }
        }
    }

    grid_barrier(&bar[3], NBLK);

    // ---- P5: out[e] = s/(s+e^-eps) ----
    {
        const float c = 0.9999900000499999f;   // exp(-1e-5)
        if (t < npair) {
            const int4 p = reinterpret_cast<const int4*>(eidx)[t];
            const float sa = snode[p.x];
            const float sb = snode[p.z];
            float2 o = { sa / (sa + c), sb / (sb + c) };
            reinterpret_cast<float2*>(out)[t] = o;
        }
        if ((nEdges & 1) && t == npair) {
            const float s = snode[eidx[2 * npair]];
            out[2 * npair] = s / (s + c);
        }
    }
}

extern "C" void kernel_launch(void* const* d_in, const int* in_sizes, int n_in,
                              void* d_out, int out_size, void* d_ws, size_t ws_size,
                              hipStream_t stream) {
    const float* embed  = (const float*)d_in[0];
    const float* weight = (const float*)d_in[1];
    const int*   eidx   = (const int*)d_in[2];
    float* out = (float*)d_out;

    int nEdges = in_sizes[1];            // weight is (E,1)
    int nNodes = in_sizes[0] / D;        // embed is (N,128)

    float* wsum     = (float*)d_ws;                      // [nNodes]
    float* btw      = wsum + nNodes;                     // [128]
    float* partialT = btw + D;                           // [D][NBLK]
    float* snode    = partialT + (size_t)D * NBLK;       // [nNodes]
    int*   bar      = (int*)(snode + nNodes);            // [4]

    const int zBlocks = (nNodes + 255) / 256;
    zero_kernel<<<zBlocks, 256, 0, stream>>>(wsum, nNodes, bar);

    void* args[] = {
        (void*)&embed, (void*)&weight, (void*)&eidx, (void*)&out,
        (void*)&wsum, (void*)&btw, (void*)&partialT, (void*)&snode,
        (void*)&bar, (void*)&nNodes, (void*)&nEdges
    };
    hipLaunchKernelGGL(fused_kernel, dim3(NBLK), dim3(NT), 0, stream,
                       embed, weight, eidx, out, wsum, btw, partialT, snode,
                       bar, nNodes, nEdges);
    (void)args;
}

// Round 10
// 94.976 us; speedup vs baseline: 8.3151x; 8.3151x over previous
//
#include <hip/hip_runtime.h>

#define D 128
#define EPS 1e-5f
#define SCAN_ROWS 8          // consecutive rows per half-wave
#define HW_PER_BLK 8         // 256 threads = 8 half-waves
#define PAD 16               // btwPad[d*PAD]: one 64B line per dim

// k0: zero wsum[nNodes] + btwPad[D*PAD]
__global__ __launch_bounds__(256) void zero_kernel(
    float4* __restrict__ p, int n4)
{
    const int i = blockIdx.x * blockDim.x + threadIdx.x;
    if (i < n4) p[i] = {0.f, 0.f, 0.f, 0.f};
}

// k1: wsum[dst_e] += w_e   (4 edges per thread)
__global__ __launch_bounds__(256) void wsum_kernel(
    const float* __restrict__ weight,
    const int* __restrict__ eidx,
    float* __restrict__ wsum,     // [nNodes], pre-zeroed
    int nEdges)
{
    const int t = blockIdx.x * blockDim.x + threadIdx.x;
    const int e0 = 4 * t;
    if (e0 + 3 < nEdges) {
        const int4 p0 = reinterpret_cast<const int4*>(eidx)[2 * t];
        const int4 p1 = reinterpret_cast<const int4*>(eidx)[2 * t + 1];
        const float4 w = reinterpret_cast<const float4*>(weight)[t];
        unsafeAtomicAdd(&wsum[p0.y], w.x);
        unsafeAtomicAdd(&wsum[p0.w], w.y);
        unsafeAtomicAdd(&wsum[p1.y], w.z);
        unsafeAtomicAdd(&wsum[p1.w], w.w);
    } else {
        for (int e = e0; e < nEdges; ++e)
            unsafeAtomicAdd(&wsum[eidx[2 * e + 1]], weight[e]);
    }
}

// k2: per-block partial column sums -> unsafeAtomicAdd into btwPad (1 line/dim)
__global__ __launch_bounds__(256, 8) void btw_partial_kernel(
    const float* __restrict__ embed,
    const float* __restrict__ wsum,
    float* __restrict__ btwPad,     // [D*PAD], pre-zeroed
    int nNodes)
{
    __shared__ float sbtw[D];
    const int tid = threadIdx.x;
    for (int i = tid; i < D; i += 256) sbtw[i] = 0.f;
    __syncthreads();

    const int j  = tid & 31;                        // lane -> dims 4j..4j+3
    const int hw = blockIdx.x * HW_PER_BLK + (tid >> 5);
    const int n0 = hw * SCAN_ROWS;

    float4 acc = {0.f, 0.f, 0.f, 0.f};
    if (n0 + SCAN_ROWS <= nNodes) {
        float4 v[SCAN_ROWS];
        float  w[SCAN_ROWS];
        #pragma unroll
        for (int r = 0; r < SCAN_ROWS; ++r)
            v[r] = reinterpret_cast<const float4*>(embed + (size_t)(n0 + r) * D)[j];
        #pragma unroll
        for (int r = 0; r < SCAN_ROWS; ++r)
            w[r] = wsum[n0 + r];
        #pragma unroll
        for (int r = 0; r < SCAN_ROWS; ++r) {
            acc.x += w[r] * v[r].x;
            acc.y += w[r] * v[r].y;
            acc.z += w[r] * v[r].z;
            acc.w += w[r] * v[r].w;
        }
    } else {
        for (int r = 0; r < SCAN_ROWS && n0 + r < nNodes; ++r) {
            const float  w = wsum[n0 + r];
            const float4 v = reinterpret_cast<const float4*>(embed + (size_t)(n0 + r) * D)[j];
            acc.x += w * v.x; acc.y += w * v.y; acc.z += w * v.z; acc.w += w * v.w;
        }
    }

    atomicAdd(&sbtw[4*j+0], acc.x);
    atomicAdd(&sbtw[4*j+1], acc.y);
    atomicAdd(&sbtw[4*j+2], acc.z);
    atomicAdd(&sbtw[4*j+3], acc.w);
    __syncthreads();
    // 128 dims x nScanBlk atomics, each dim on its OWN 64B line -> parallel
    // across L2 channels, ~1563 serialized adds per line, block-staggered.
    if (tid < D) unsafeAtomicAdd(&btwPad[tid * PAD], sbtw[tid]);
}

// k3: snode[n] = dot(embed[n,:], btw), 8 consecutive rows in flight
__global__ __launch_bounds__(256, 8) void snode_kernel(
    const float* __restrict__ embed,
    const float* __restrict__ btwPad,
    float* __restrict__ snode,
    int nNodes)
{
    const int tid = threadIdx.x;
    const int j = tid & 31;
    const float4 bt = { btwPad[(4*j+0) * PAD], btwPad[(4*j+1) * PAD],
                        btwPad[(4*j+2) * PAD], btwPad[(4*j+3) * PAD] };
    const int hw = blockIdx.x * HW_PER_BLK + (tid >> 5);
    const int n0 = hw * SCAN_ROWS;

    if (n0 + SCAN_ROWS <= nNodes) {
        float4 v[SCAN_ROWS];
        #pragma unroll
        for (int r = 0; r < SCAN_ROWS; ++r)
            v[r] = reinterpret_cast<const float4*>(embed + (size_t)(n0 + r) * D)[j];
        float s[SCAN_ROWS];
        #pragma unroll
        for (int r = 0; r < SCAN_ROWS; ++r)
            s[r] = v[r].x*bt.x + v[r].y*bt.y + v[r].z*bt.z + v[r].w*bt.w;
        #pragma unroll
        for (int m = 1; m < 32; m <<= 1) {
            #pragma unroll
            for (int r = 0; r < SCAN_ROWS; ++r)
                s[r] += __shfl_xor(s[r], m, 64);
        }
        if (j == 0) {
            float4 o0 = {s[0], s[1], s[2], s[3]};
            float4 o1 = {s[4], s[5], s[6], s[7]};
            reinterpret_cast<float4*>(snode + n0)[0] = o0;
            reinterpret_cast<float4*>(snode + n0)[1] = o1;
        }
    } else if (n0 < nNodes) {
        for (int r = 0; r < SCAN_ROWS && n0 + r < nNodes; ++r) {
            const float4 v = reinterpret_cast<const float4*>(embed + (size_t)(n0 + r) * D)[j];
            float s = v.x*bt.x + v.y*bt.y + v.z*bt.z + v.w*bt.w;
            #pragma unroll
            for (int m = 1; m < 32; m <<= 1) s += __shfl_xor(s, m, 64);
            if (j == 0) snode[n0 + r] = s;
        }
    }
}

// k4: out[e] = s/(s+e^-eps), 4 edges per thread
__global__ __launch_bounds__(256) void out_kernel(
    const int* __restrict__ eidx,
    const float* __restrict__ snode,
    float* __restrict__ out,
    int nEdges)
{
    const float c = 0.9999900000499999f;   // exp(-EPS)
    const int t = blockIdx.x * blockDim.x + threadIdx.x;
    const int e0 = 4 * t;
    if (e0 + 3 < nEdges) {
        const int4 p0 = reinterpret_cast<const int4*>(eidx)[2 * t];
        const int4 p1 = reinterpret_cast<const int4*>(eidx)[2 * t + 1];
        const float s0 = snode[p0.x];
        const float s1 = snode[p0.z];
        const float s2 = snode[p1.x];
        const float s3 = snode[p1.z];
        float4 o = { s0 / (s0 + c), s1 / (s1 + c),
                     s2 / (s2 + c), s3 / (s3 + c) };
        reinterpret_cast<float4*>(out)[t] = o;
    } else {
        for (int e = e0; e < nEdges; ++e) {
            const float s = snode[eidx[2 * e]];
            out[e] = s / (s + c);
        }
    }
}

extern "C" void kernel_launch(void* const* d_in, const int* in_sizes, int n_in,
                              void* d_out, int out_size, void* d_ws, size_t ws_size,
                              hipStream_t stream) {
    const float* embed  = (const float*)d_in[0];
    const float* weight = (const float*)d_in[1];
    const int*   eidx   = (const int*)d_in[2];
    float* out = (float*)d_out;

    const int nEdges = in_sizes[1];          // weight is (E,1)
    const int nNodes = in_sizes[0] / D;      // embed is (N,128)

    float* wsum   = (float*)d_ws;            // [nNodes]
    float* btwPad = wsum + nNodes;           // [D*PAD] = 8 KB
    float* snode  = btwPad + D * PAD;        // [nNodes]

    const int nZero4   = (nNodes + D * PAD + 3) / 4;
    const int zBlocks  = (nZero4 + 255) / 256;
    const int eBlocks4 = ((nEdges + 3) / 4 + 255) / 256;
    const int nScanBlk = (nNodes + SCAN_ROWS * HW_PER_BLK - 1) / (SCAN_ROWS * HW_PER_BLK);

    zero_kernel       <<<zBlocks,  256, 0, stream>>>((float4*)d_ws, nZero4);
    wsum_kernel       <<<eBlocks4, 256, 0, stream>>>(weight, eidx, wsum, nEdges);
    btw_partial_kernel<<<nScanBlk, 256, 0, stream>>>(embed, wsum, btwPad, nNodes);
    snode_kernel      <<<nScanBlk, 256, 0, stream>>>(embed, btwPad, snode, nNodes);
    out_kernel        <<<eBlocks4, 256, 0, stream>>>(eidx, snode, out, nEdges);
}

// Round 11
// 74.782 us; speedup vs baseline: 10.5605x; 1.2700x over previous
//
#include <hip/hip_runtime.h>

#define D 128
#define EPS 1e-5f
#define SCAN_ROWS 8          // consecutive rows per half-wave
#define HW_PER_BLK 8         // 256 threads = 8 half-waves
#define NREP 16              // btw replicas (serial atomic depth ~= nScanBlk/NREP)
#define RSTRIDE 16           // floats: one 64B line per (rep,dim)

// k0: zero wsum[nNodes] + btwR[NREP][D*RSTRIDE]
__global__ __launch_bounds__(256) void zero_kernel(
    float4* __restrict__ p, int n4)
{
    const int i = blockIdx.x * blockDim.x + threadIdx.x;
    if (i < n4) p[i] = {0.f, 0.f, 0.f, 0.f};
}

// k1: wsum[dst_e] += w_e   (4 edges per thread)
__global__ __launch_bounds__(256) void wsum_kernel(
    const float* __restrict__ weight,
    const int* __restrict__ eidx,
    float* __restrict__ wsum,     // [nNodes], pre-zeroed
    int nEdges)
{
    const int t = blockIdx.x * blockDim.x + threadIdx.x;
    const int e0 = 4 * t;
    if (e0 + 3 < nEdges) {
        const int4 p0 = reinterpret_cast<const int4*>(eidx)[2 * t];
        const int4 p1 = reinterpret_cast<const int4*>(eidx)[2 * t + 1];
        const float4 w = reinterpret_cast<const float4*>(weight)[t];
        unsafeAtomicAdd(&wsum[p0.y], w.x);
        unsafeAtomicAdd(&wsum[p0.w], w.y);
        unsafeAtomicAdd(&wsum[p1.y], w.z);
        unsafeAtomicAdd(&wsum[p1.w], w.w);
    } else {
        for (int e = e0; e < nEdges; ++e)
            unsafeAtomicAdd(&wsum[eidx[2 * e + 1]], weight[e]);
    }
}

// k2: per-block partial column sums -> atomic into btwR[blockIdx%NREP][d]
//     (each (rep,dim) on its own 64B line; serial depth ~nScanBlk/NREP)
__global__ __launch_bounds__(256, 8) void btw_partial_kernel(
    const float* __restrict__ embed,
    const float* __restrict__ wsum,
    float* __restrict__ btwR,       // [NREP][D*RSTRIDE], pre-zeroed
    int nNodes)
{
    __shared__ float sbtw[D];
    const int tid = threadIdx.x;
    for (int i = tid; i < D; i += 256) sbtw[i] = 0.f;
    __syncthreads();

    const int j  = tid & 31;                        // lane -> dims 4j..4j+3
    const int hw = blockIdx.x * HW_PER_BLK + (tid >> 5);
    const int n0 = hw * SCAN_ROWS;

    float4 acc = {0.f, 0.f, 0.f, 0.f};
    if (n0 + SCAN_ROWS <= nNodes) {
        float4 v[SCAN_ROWS];
        float  w[SCAN_ROWS];
        #pragma unroll
        for (int r = 0; r < SCAN_ROWS; ++r)
            v[r] = reinterpret_cast<const float4*>(embed + (size_t)(n0 + r) * D)[j];
        #pragma unroll
        for (int r = 0; r < SCAN_ROWS; ++r)
            w[r] = wsum[n0 + r];
        #pragma unroll
        for (int r = 0; r < SCAN_ROWS; ++r) {
            acc.x += w[r] * v[r].x;
            acc.y += w[r] * v[r].y;
            acc.z += w[r] * v[r].z;
            acc.w += w[r] * v[r].w;
        }
    } else {
        for (int r = 0; r < SCAN_ROWS && n0 + r < nNodes; ++r) {
            const float  w = wsum[n0 + r];
            const float4 v = reinterpret_cast<const float4*>(embed + (size_t)(n0 + r) * D)[j];
            acc.x += w * v.x; acc.y += w * v.y; acc.z += w * v.z; acc.w += w * v.w;
        }
    }

    atomicAdd(&sbtw[4*j+0], acc.x);
    atomicAdd(&sbtw[4*j+1], acc.y);
    atomicAdd(&sbtw[4*j+2], acc.z);
    atomicAdd(&sbtw[4*j+3], acc.w);
    __syncthreads();
    if (tid < D) {
        float* dst = btwR + (size_t)(blockIdx.x & (NREP - 1)) * (D * RSTRIDE)
                          + tid * RSTRIDE;
        unsafeAtomicAdd(dst, sbtw[tid]);
    }
}

// k3: snode[n] = dot(embed[n,:], btw); prologue collapses the NREP replicas
__global__ __launch_bounds__(256, 8) void snode_kernel(
    const float* __restrict__ embed,
    const float* __restrict__ btwR,
    float* __restrict__ snode,
    int nNodes)
{
    __shared__ float sbt[D];
    const int tid = threadIdx.x;
    if (tid < D) {
        float s = 0.f;
        #pragma unroll
        for (int r = 0; r < NREP; ++r)
            s += btwR[(size_t)r * (D * RSTRIDE) + tid * RSTRIDE];
        sbt[tid] = s;
    }
    __syncthreads();

    const int j = tid & 31;
    const float4 bt = { sbt[4*j+0], sbt[4*j+1], sbt[4*j+2], sbt[4*j+3] };
    const int hw = blockIdx.x * HW_PER_BLK + (tid >> 5);
    const int n0 = hw * SCAN_ROWS;

    if (n0 + SCAN_ROWS <= nNodes) {
        float4 v[SCAN_ROWS];
        #pragma unroll
        for (int r = 0; r < SCAN_ROWS; ++r)
            v[r] = reinterpret_cast<const float4*>(embed + (size_t)(n0 + r) * D)[j];
        float s[SCAN_ROWS];
        #pragma unroll
        for (int r = 0; r < SCAN_ROWS; ++r)
            s[r] = v[r].x*bt.x + v[r].y*bt.y + v[r].z*bt.z + v[r].w*bt.w;
        #pragma unroll
        for (int m = 1; m < 32; m <<= 1) {
            #pragma unroll
            for (int r = 0; r < SCAN_ROWS; ++r)
                s[r] += __shfl_xor(s[r], m, 64);
        }
        if (j == 0) {
            float4 o0 = {s[0], s[1], s[2], s[3]};
            float4 o1 = {s[4], s[5], s[6], s[7]};
            reinterpret_cast<float4*>(snode + n0)[0] = o0;
            reinterpret_cast<float4*>(snode + n0)[1] = o1;
        }
    } else if (n0 < nNodes) {
        for (int r = 0; r < SCAN_ROWS && n0 + r < nNodes; ++r) {
            const float4 v = reinterpret_cast<const float4*>(embed + (size_t)(n0 + r) * D)[j];
            float s = v.x*bt.x + v.y*bt.y + v.z*bt.z + v.w*bt.w;
            #pragma unroll
            for (int m = 1; m < 32; m <<= 1) s += __shfl_xor(s, m, 64);
            if (j == 0) snode[n0 + r] = s;
        }
    }
}

// k4: out[e] = s/(s+e^-eps), 4 edges per thread
__global__ __launch_bounds__(256) void out_kernel(
    const int* __restrict__ eidx,
    const float* __restrict__ snode,
    float* __restrict__ out,
    int nEdges)
{
    const float c = 0.9999900000499999f;   // exp(-EPS)
    const int t = blockIdx.x * blockDim.x + threadIdx.x;
    const int e0 = 4 * t;
    if (e0 + 3 < nEdges) {
        const int4 p0 = reinterpret_cast<const int4*>(eidx)[2 * t];
        const int4 p1 = reinterpret_cast<const int4*>(eidx)[2 * t + 1];
        const float s0 = snode[p0.x];
        const float s1 = snode[p0.z];
        const float s2 = snode[p1.x];
        const float s3 = snode[p1.z];
        float4 o = { s0 / (s0 + c), s1 / (s1 + c),
                     s2 / (s2 + c), s3 / (s3 + c) };
        reinterpret_cast<float4*>(out)[t] = o;
    } else {
        for (int e = e0; e < nEdges; ++e) {
            const float s = snode[eidx[2 * e]];
            out[e] = s / (s + c);
        }
    }
}

extern "C" void kernel_launch(void* const* d_in, const int* in_sizes, int n_in,
                              void* d_out, int out_size, void* d_ws, size_t ws_size,
                              hipStream_t stream) {
    const float* embed  = (const float*)d_in[0];
    const float* weight = (const float*)d_in[1];
    const int*   eidx   = (const int*)d_in[2];
    float* out = (float*)d_out;

    const int nEdges = in_sizes[1];          // weight is (E,1)
    const int nNodes = in_sizes[0] / D;      // embed is (N,128)

    float* wsum  = (float*)d_ws;                     // [nNodes]
    float* btwR  = wsum + nNodes;                    // [NREP][D*RSTRIDE] = 128 KB
    float* snode = btwR + NREP * D * RSTRIDE;        // [nNodes]

    const int nZero4   = (nNodes + NREP * D * RSTRIDE + 3) / 4;
    const int zBlocks  = (nZero4 + 255) / 256;
    const int eBlocks4 = ((nEdges + 3) / 4 + 255) / 256;
    const int nScanBlk = (nNodes + SCAN_ROWS * HW_PER_BLK - 1) / (SCAN_ROWS * HW_PER_BLK);

    zero_kernel       <<<zBlocks,  256, 0, stream>>>((float4*)d_ws, nZero4);
    wsum_kernel       <<<eBlocks4, 256, 0, stream>>>(weight, eidx, wsum, nEdges);
    btw_partial_kernel<<<nScanBlk, 256, 0, stream>>>(embed, wsum, btwR, nNodes);
    snode_kernel      <<<nScanBlk, 256, 0, stream>>>(embed, btwR, snode, nNodes);
    out_kernel        <<<eBlocks4, 256, 0, stream>>>(eidx, snode, out, nEdges);
}

// Round 12
// 67.892 us; speedup vs baseline: 11.6322x; 1.1015x over previous
//
#include <hip/hip_runtime.h>

#define D 128
#define EPS 1e-5f
#define SCAN_ROWS 8          // consecutive rows per half-wave
#define HW_PER_BLK 8         // 256 threads = 8 half-waves

// k0: zero wsum[nNodes]
__global__ __launch_bounds__(256) void zero_kernel(
    float4* __restrict__ p, int n4)
{
    const int i = blockIdx.x * blockDim.x + threadIdx.x;
    if (i < n4) p[i] = {0.f, 0.f, 0.f, 0.f};
}

// k1: wsum[dst_e] += w_e   (4 edges per thread, vectorized reads)
__global__ __launch_bounds__(256) void wsum_kernel(
    const float* __restrict__ weight,
    const int* __restrict__ eidx,
    float* __restrict__ wsum,     // [nNodes], pre-zeroed
    int nEdges)
{
    const int t = blockIdx.x * blockDim.x + threadIdx.x;
    const int e0 = 4 * t;
    if (e0 + 3 < nEdges) {
        const int4 p0 = reinterpret_cast<const int4*>(eidx)[2 * t];
        const int4 p1 = reinterpret_cast<const int4*>(eidx)[2 * t + 1];
        const float4 w = reinterpret_cast<const float4*>(weight)[t];
        unsafeAtomicAdd(&wsum[p0.y], w.x);
        unsafeAtomicAdd(&wsum[p0.w], w.y);
        unsafeAtomicAdd(&wsum[p1.y], w.z);
        unsafeAtomicAdd(&wsum[p1.w], w.w);
    } else {
        for (int e = e0; e < nEdges; ++e)
            unsafeAtomicAdd(&wsum[eidx[2 * e + 1]], weight[e]);
    }
}

// k2a: per-block partial column sums, 8 consecutive rows per half-wave
__global__ __launch_bounds__(256, 8) void btw_partial_kernel(
    const float* __restrict__ embed,
    const float* __restrict__ wsum,
    float* __restrict__ partialT,   // [D][nScanBlk]
    int nNodes, int nScanBlk)
{
    __shared__ float sbtw[D];
    const int tid = threadIdx.x;
    for (int i = tid; i < D; i += 256) sbtw[i] = 0.f;
    __syncthreads();

    const int j  = tid & 31;                        // lane -> dims 4j..4j+3
    const int hw = blockIdx.x * HW_PER_BLK + (tid >> 5);
    const int n0 = hw * SCAN_ROWS;

    float4 acc = {0.f, 0.f, 0.f, 0.f};
    if (n0 + SCAN_ROWS <= nNodes) {
        float4 v[SCAN_ROWS];
        float  w[SCAN_ROWS];
        #pragma unroll
        for (int r = 0; r < SCAN_ROWS; ++r)
            v[r] = reinterpret_cast<const float4*>(embed + (size_t)(n0 + r) * D)[j];
        #pragma unroll
        for (int r = 0; r < SCAN_ROWS; ++r)
            w[r] = wsum[n0 + r];
        #pragma unroll
        for (int r = 0; r < SCAN_ROWS; ++r) {
            acc.x += w[r] * v[r].x;
            acc.y += w[r] * v[r].y;
            acc.z += w[r] * v[r].z;
            acc.w += w[r] * v[r].w;
        }
    } else {
        for (int r = 0; r < SCAN_ROWS && n0 + r < nNodes; ++r) {
            const float  w = wsum[n0 + r];
            const float4 v = reinterpret_cast<const float4*>(embed + (size_t)(n0 + r) * D)[j];
            acc.x += w * v.x; acc.y += w * v.y; acc.z += w * v.z; acc.w += w * v.w;
        }
    }

    atomicAdd(&sbtw[4*j+0], acc.x);
    atomicAdd(&sbtw[4*j+1], acc.y);
    atomicAdd(&sbtw[4*j+2], acc.z);
    atomicAdd(&sbtw[4*j+3], acc.w);
    __syncthreads();
    if (tid < D) partialT[(size_t)tid * nScanBlk + blockIdx.x] = sbtw[tid];
}

// k2b: btw[d] = sum_b partialT[d][b]
__global__ __launch_bounds__(256) void btw_reduce_kernel(
    const float* __restrict__ partialT,
    float* __restrict__ btw,
    int nScanBlk)
{
    __shared__ float red[256];
    const int d = blockIdx.x;
    const int tid = threadIdx.x;
    float s = 0.f;
    const float* row = partialT + (size_t)d * nScanBlk;
    for (int k = tid; k < nScanBlk; k += 256) s += row[k];
    red[tid] = s;
    __syncthreads();
    for (int off = 128; off > 0; off >>= 1) {
        if (tid < off) red[tid] += red[tid + off];
        __syncthreads();
    }
    if (tid == 0) btw[d] = red[0];
}

// k3: snode[n] = dot(embed[n,:], btw), 8 consecutive rows per half-wave
__global__ __launch_bounds__(256, 8) void snode_kernel(
    const float* __restrict__ embed,
    const float* __restrict__ btw,
    float* __restrict__ snode,
    int nNodes)
{
    const int tid = threadIdx.x;
    const int j = tid & 31;
    const float4 bt = reinterpret_cast<const float4*>(btw)[j];
    const int hw = blockIdx.x * HW_PER_BLK + (tid >> 5);
    const int n0 = hw * SCAN_ROWS;

    if (n0 + SCAN_ROWS <= nNodes) {
        float4 v[SCAN_ROWS];
        #pragma unroll
        for (int r = 0; r < SCAN_ROWS; ++r)
            v[r] = reinterpret_cast<const float4*>(embed + (size_t)(n0 + r) * D)[j];
        float s[SCAN_ROWS];
        #pragma unroll
        for (int r = 0; r < SCAN_ROWS; ++r)
            s[r] = v[r].x*bt.x + v[r].y*bt.y + v[r].z*bt.z + v[r].w*bt.w;
        #pragma unroll
        for (int m = 1; m < 32; m <<= 1) {
            #pragma unroll
            for (int r = 0; r < SCAN_ROWS; ++r)
                s[r] += __shfl_xor(s[r], m, 64);
        }
        if (j == 0) {
            float4 o0 = {s[0], s[1], s[2], s[3]};
            float4 o1 = {s[4], s[5], s[6], s[7]};
            reinterpret_cast<float4*>(snode + n0)[0] = o0;
            reinterpret_cast<float4*>(snode + n0)[1] = o1;
        }
    } else if (n0 < nNodes) {
        for (int r = 0; r < SCAN_ROWS && n0 + r < nNodes; ++r) {
            const float4 v = reinterpret_cast<const float4*>(embed + (size_t)(n0 + r) * D)[j];
            float s = v.x*bt.x + v.y*bt.y + v.z*bt.z + v.w*bt.w;
            #pragma unroll
            for (int m = 1; m < 32; m <<= 1) s += __shfl_xor(s, m, 64);
            if (j == 0) snode[n0 + r] = s;
        }
    }
}

// k4: out[e] = s/(s+e^-eps), 4 edges per thread
__global__ __launch_bounds__(256) void out_kernel(
    const int* __restrict__ eidx,
    const float* __restrict__ snode,
    float* __restrict__ out,
    int nEdges)
{
    const float c = 0.9999900000499999f;   // exp(-EPS)
    const int t = blockIdx.x * blockDim.x + threadIdx.x;
    const int e0 = 4 * t;
    if (e0 + 3 < nEdges) {
        const int4 p0 = reinterpret_cast<const int4*>(eidx)[2 * t];
        const int4 p1 = reinterpret_cast<const int4*>(eidx)[2 * t + 1];
        const float s0 = snode[p0.x];
        const float s1 = snode[p0.z];
        const float s2 = snode[p1.x];
        const float s3 = snode[p1.z];
        float4 o = { s0 / (s0 + c), s1 / (s1 + c),
                     s2 / (s2 + c), s3 / (s3 + c) };
        reinterpret_cast<float4*>(out)[t] = o;
    } else {
        for (int e = e0; e < nEdges; ++e) {
            const float s = snode[eidx[2 * e]];
            out[e] = s / (s + c);
        }
    }
}

extern "C" void kernel_launch(void* const* d_in, const int* in_sizes, int n_in,
                              void* d_out, int out_size, void* d_ws, size_t ws_size,
                              hipStream_t stream) {
    const float* embed  = (const float*)d_in[0];
    const float* weight = (const float*)d_in[1];
    const int*   eidx   = (const int*)d_in[2];
    float* out = (float*)d_out;

    const int nEdges = in_sizes[1];          // weight is (E,1)
    const int nNodes = in_sizes[0] / D;      // embed is (N,128)

    float* wsum     = (float*)d_ws;          // [nNodes]
    float* btw      = wsum + nNodes;         // [128]
    float* snode    = btw + D;               // [nNodes]
    float* partialT = snode + nNodes;        // [D][nScanBlk]

    const int nZero4   = (nNodes + 3) / 4;
    const int zBlocks  = (nZero4 + 255) / 256;
    const int eBlocks4 = ((nEdges + 3) / 4 + 255) / 256;
    const int nScanBlk = (nNodes + SCAN_ROWS * HW_PER_BLK - 1) / (SCAN_ROWS * HW_PER_BLK);

    zero_kernel       <<<zBlocks,  256, 0, stream>>>((float4*)d_ws, nZero4);
    wsum_kernel       <<<eBlocks4, 256, 0, stream>>>(weight, eidx, wsum, nEdges);
    btw_partial_kernel<<<nScanBlk, 256, 0, stream>>>(embed, wsum, partialT, nNodes, nScanBlk);
    btw_reduce_kernel <<<D,        256, 0, stream>>>(partialT, btw, nScanBlk);
    snode_kernel      <<<nScanBlk, 256, 0, stream>>>(embed, btw, snode, nNodes);
    out_kernel        <<<eBlocks4, 256, 0, stream>>>(eidx, snode, out, nEdges);
}